// Round 15
// baseline (239.755 us; speedup 1.0000x reference)
//
#include <hip/hip_runtime.h>
#include <math.h>
#include <stdint.h>

#define NSPH 7
#define NRAD 6
#define BLK  256
#define EPB2 10     // edges per edge_k block (448 threads = 7 waves x 10x6)
#define NE_PAD 48   // padded table row: 192 B (64B-aligned rows)

typedef float f32x2 __attribute__((ext_vector_type(2)));
typedef float f32x4 __attribute__((ext_vector_type(4)));

// ===== glibc sinf/cosf bit-exact replication =====
// (glibc sysdeps/ieee754/flt-32, baseline x86-64: f64 internals, NO fma)
// verified PASS rounds 3-13.
#define SC_HPI_INV 0x1.45F306DC9C883p+23   /* 2/pi * 2^24 */
#define SC_HPI     0x1.921FB54442D18p+0
#define SC_C0      (0x1p+0)
#define SC_C1      (-0x1.ffffffd0c621cp-2)
#define SC_C2      (0x1.55553e1068f19p-5)
#define SC_C3      (-0x1.6c087e89a359dp-10)
#define SC_C4      (0x1.99343027bf8c3p-16)
#define SC_S1      (-0x1.555545995a603p-3)
#define SC_S2      (0x1.1107605230bc4p-7)
#define SC_S3      (-0x1.994eb3774cf24p-13)

__device__ __forceinline__ unsigned abstop12(float x) {
    return (__float_as_uint(x) >> 20) & 0x7ffu;
}

__device__ __forceinline__ float sp_sin(double x, double x2) {
    double x3 = __dmul_rn(x, x2);
    double s1 = __dadd_rn(SC_S2, __dmul_rn(x2, SC_S3));
    double x7 = __dmul_rn(x3, x2);
    double s  = __dadd_rn(x, __dmul_rn(x3, SC_S1));
    return (float)__dadd_rn(s, __dmul_rn(x7, s1));
}

__device__ __forceinline__ float sp_cos(double x2, bool neg) {
    double c0 = neg ? -SC_C0 : SC_C0;
    double c1 = neg ? -SC_C1 : SC_C1;
    double c2 = neg ? -SC_C2 : SC_C2;
    double c3 = neg ? -SC_C3 : SC_C3;
    double c4 = neg ? -SC_C4 : SC_C4;
    double x4  = __dmul_rn(x2, x2);
    double c2v = __dadd_rn(c3, __dmul_rn(x2, c4));
    double c1v = __dadd_rn(c0, __dmul_rn(x2, c1));
    double x6  = __dmul_rn(x4, x2);
    double c   = __dadd_rn(c1v, __dmul_rn(x4, c2));
    return (float)__dadd_rn(c, __dmul_rn(x6, c2v));
}

// positive-coefficient cosine poly (sp_cos(x2,false))
__device__ __forceinline__ float sp_cos_pos(double x2) {
    double x4  = __dmul_rn(x2, x2);
    double c2v = __dadd_rn(SC_C3, __dmul_rn(x2, SC_C4));
    double c1v = __dadd_rn(SC_C0, __dmul_rn(x2, SC_C1));
    double x6  = __dmul_rn(x4, x2);
    double c   = __dadd_rn(c1v, __dmul_rn(x4, SC_C2));
    return (float)__dadd_rn(c, __dmul_rn(x6, c2v));
}

__device__ __forceinline__ double reduce_fast(double x, int* np) {
    double r = __dmul_rn(x, SC_HPI_INV);
    int n = (((int)r) + 0x800000) >> 24;
    *np = n;
    return __dsub_rn(x, __dmul_rn((double)n, SC_HPI));
}

__device__ __forceinline__ float glibc_cosf(float y) {
    unsigned at = abstop12(y);
    double x = (double)y;
    if (at < 0x3f4u) {
        if (at < 0x398u) return 1.0f;
        return sp_cos(__dmul_rn(x, x), false);
    }
    int n;
    double r = reduce_fast(x, &n);
    double s = ((n + 2) & 2) ? -1.0 : 1.0;
    bool neg = ((n + 1) & 2) != 0;
    int m = n ^ 1;
    double xs = __dmul_rn(r, s);
    double x2 = __dmul_rn(r, r);
    if ((m & 1) == 0) return sp_sin(xs, x2);
    return sp_cos(x2, neg);
}

// BOTH sinf(y) and cosf(y) with one reduce_fast; bit-identical to glibc calls.
__device__ __forceinline__ void glibc_sincosf(float y, float& so, float& co) {
    unsigned at = abstop12(y);
    double x = (double)y;
    if (at < 0x3f4u) {
        if (at < 0x398u) { so = y; co = 1.0f; return; }
        double x2 = __dmul_rn(x, x);
        so = sp_sin(x, x2);
        co = sp_cos(x2, false);
        return;
    }
    int n;
    double r = reduce_fast(x, &n);
    double x2 = __dmul_rn(r, r);
    double ss = ((n + 1) & 2) ? -1.0 : 1.0;
    double cs = ((n + 2) & 2) ? -1.0 : 1.0;
    bool sneg = (n & 2) != 0;
    bool cneg = ((n + 1) & 2) != 0;
    if ((n & 1) == 0) {
        so = sp_sin(__dmul_rn(r, ss), x2);
        co = sp_cos(x2, cneg);
    } else {
        so = sp_cos(x2, sneg);
        co = sp_sin(__dmul_rn(r, cs), x2);
    }
}

// Branch-free sincos for 2^-12 < x < 0.78125..117435 range (edge_k's x).
// Bit-identical to glibc_sincosf there (verified PASS rounds 10-13).
__device__ __forceinline__ void sincos_nr(float y, float& so, float& co) {
    int n;
    double r = reduce_fast((double)y, &n);
    double x2 = __dmul_rn(r, r);
    float sps = sp_sin(r, x2);      // sin(r) rounded to f32
    float spc = sp_cos_pos(x2);     // cos(r) rounded to f32
    unsigned sbit = (unsigned)(n & 2) << 30;          // sin negative iff n&2
    unsigned cbit = (unsigned)((n + 1) & 2) << 30;    // cos negative iff (n+1)&2
    bool odd = (n & 1) != 0;
    float sv = odd ? spc : sps;
    float cv = odd ? sps : spc;
    so = __uint_as_float(__float_as_uint(sv) ^ sbit);
    co = __uint_as_float(__float_as_uint(cv) ^ cbit);
}

// ===== fast f64 sincos for setup_k (0 < x < 64), abs err ~1e-16 ======
// Replaces device-libm sin/cos (Payne-Hanek, ~1us serial latency) on the
// single-block bisection critical path. Root sign-tests tolerate ~1e-12
// eval error; converged roots only need ~1e-10 (f32-cast safety margin).
__device__ __forceinline__ void sincos_f64(double x, double& so, double& co) {
    const double TOPI   = 0.63661977236758138;      // 2/pi
    const double P2_H   = 1.5707963267341256e+00;   // pi/2 hi (33 bits)
    const double P2_M   = 6.0771005065061922e-11;   // pi/2 med
    const double P2_L   = 2.0222662487959506e-21;   // pi/2 lo
    const double RSHIFT = 6755399441055744.0;       // 1.5*2^52
    double fn = __dsub_rn(__fma_rn(x, TOPI, RSHIFT), RSHIFT);  // rne(x*2/pi)
    int n = (int)fn;
    double r = __fma_rn(-fn, P2_H, x);
    r = __fma_rn(-fn, P2_M, r);
    r = __fma_rn(-fn, P2_L, r);
    double r2 = __dmul_rn(r, r);
    // sin(r), odd Taylor through r^15
    double sp = -7.6471637318198165e-13;
    sp = __fma_rn(sp, r2,  1.6059043836821613e-10);
    sp = __fma_rn(sp, r2, -2.5052108385441720e-08);
    sp = __fma_rn(sp, r2,  2.7557319223985893e-06);
    sp = __fma_rn(sp, r2, -1.9841269841269841e-04);
    sp = __fma_rn(sp, r2,  8.3333333333333333e-03);
    sp = __fma_rn(sp, r2, -1.6666666666666667e-01);
    double ss = __fma_rn(__dmul_rn(sp, r2), r, r);
    // cos(r), even Taylor through r^16
    double cp =  4.7794773323873853e-14;
    cp = __fma_rn(cp, r2, -1.1470745597729725e-11);
    cp = __fma_rn(cp, r2,  2.0876756987868099e-09);
    cp = __fma_rn(cp, r2, -2.7557319223985888e-07);
    cp = __fma_rn(cp, r2,  2.4801587301587302e-05);
    cp = __fma_rn(cp, r2, -1.3888888888888889e-03);
    cp = __fma_rn(cp, r2,  4.1666666666666666e-02);
    cp = __fma_rn(cp, r2, -5.0000000000000000e-01);
    double cc = __fma_rn(cp, r2, 1.0);
    bool odd = (n & 1) != 0;
    double sv = odd ? cc : ss;
    double cv = odd ? ss : cc;
    so = (n & 2) ? -sv : sv;
    co = ((n + 1) & 2) ? -cv : cv;
}

// ===== f64 spherical bessel (setup only; fast trig, err ~1e-15) =====
__device__ __forceinline__ double jn_f64(double x, int n) {
    double s, c;
    sincos_f64(x, s, c);
    double j0 = s / x;
    if (n == 0) return j0;
    double j1 = s / (x * x) - c / x;
    double jm1 = j0, j = j1;
    for (int l = 1; l < n; ++l) {
        double t = (double)(2 * l + 1) / x * j - jm1;
        jm1 = j; j = t;
    }
    return j;
}

// cst layout (floats): [0..41] zf, [42..83] bnorm, [84..90] ynorm
__global__ __launch_bounds__(704) void setup_k(float* __restrict__ cst) {
    __shared__ double pts[13];
    __shared__ double roots[12];
    __shared__ double Z[NSPH][NRAD];
    const double PI = 3.141592653589793238462643383279502884;
    int tid = threadIdx.x, wv = tid >> 6, ln = tid & 63;
    if (tid < 12) pts[tid] = PI * (double)(tid + 1);
    __syncthreads();
    if (tid < NRAD) Z[0][tid] = pts[tid];
    for (int i = 1; i < NSPH; ++i) {
        int m = NRAD + NSPH - 1 - i;  // 12 - i
        if (wv < m) {
            double a = pts[wv], b = pts[wv + 1];
            for (int r = 0; r < 9; ++r) {
                double st = (b - a) * (1.0 / 63.0);
                double f = jn_f64(a + st * (double)ln, i);
                double f0 = __shfl(f, 0);
                unsigned long long bm = __ballot((ln > 0) && (f0 * f <= 0.0));
                int idx = bm ? (__ffsll((unsigned long long)bm) - 1) : 63;
                b = a + st * (double)idx;
                a = a + st * (double)(idx - 1);
            }
            if (ln == 0) roots[wv] = 0.5 * (a + b);
        }
        __syncthreads();
        if (tid < m) pts[tid] = roots[tid];
        if (tid < NRAD) Z[i][tid] = roots[tid];
        __syncthreads();
    }
    if (tid < NSPH * NRAD) {
        int l = tid / NRAD;
        double z = Z[l][tid % NRAD];
        cst[tid] = (float)z;
        double jp = jn_f64(z, l + 1);
        cst[42 + tid] = (float)(1.0 / sqrt(0.5 * (jp * jp)));
    }
    if (tid < NSPH) {
        cst[84 + tid] = (float)sqrt((double)(2 * tid + 1) / (4.0 * PI));
    }
}

// ===== Phase A0: per-edge envelope, stored in table-row padding slot 47 ====
__global__ __launch_bounds__(BLK) void env_k(
    const float* __restrict__ D, float* __restrict__ tab, int nE)
{
    int e = blockIdx.x * BLK + threadIdx.x;
    if (e >= nE) return;
    float d = __fmul_rn(D[e], 0.2f);
    float invd = __fdiv_rn(1.0f, d);
    float d2 = d * d, d4 = d2 * d2, d5 = d4 * d, d6 = d5 * d, d7 = d6 * d;
    float env = ((invd + (-28.0f) * d5) + 48.0f * d6) + (-21.0f) * d7;
    float u_d = (d < 1.0f) ? env : 0.0f;
    const float NC = (float)0.0894427190999916;  // 0.2**1.5
    tab[(long long)e * NE_PAD + 47] = __fmul_rn(u_d, NC);
}

// ===== Phase A: rbf_env table; wave==l mapping (r12 structure) =====
__global__ __launch_bounds__(448) void edge_k(
    const float* __restrict__ D, const float* __restrict__ cst,
    float* __restrict__ tab, int nE)
{
    int tid = threadIdx.x;
    int l    = tid >> 6;         // wave index == level (0..6)
    int ln   = tid & 63;
    int slot = ln / 6;           // 0..10 (slot 10 + lanes 60-63 idle)
    int n    = ln - slot * 6;
    long long e = (long long)blockIdx.x * EPB2 + slot;
    if (slot >= EPB2 || e >= (long long)nE) return;
    int k = l * 6 + n;

    float d   = __fmul_rn(D[e], 0.2f);
    float unc = tab[e * NE_PAD + 47];      // env from env_k
    float z   = cst[k];
    float bnk = cst[42 + k];

    float x = __fmul_rn(d, z);   // x in (0.0063, 26.9): sincos_nr valid
    float s, c;
    sincos_nr(x, s, c);
    float j = __fdiv_rn(s, x);
    if (l > 0) {                 // wave-uniform
        float x2 = __fmul_rn(x, x);
        float j1 = __fsub_rn(__fdiv_rn(s, x2), __fdiv_rn(c, x));
        float jm1 = j, jc = j1;
        for (int kk = 1; kk < l; ++kk) {   // wave-uniform trip count
            float fk = __fdiv_rn((float)(2 * kk + 1), x);
            float jn2 = __fsub_rn(__fmul_rn(fk, jc), jm1);
            jm1 = jc; jc = jn2;
        }
        j = jc;
    }
    tab[e * NE_PAD + k] = __fmul_rn(unc, __fmul_rn(bnk, j));
}

// ===== Phase B: direct streamed gather->mul->NT store (r9-r13 structure) ====
__global__ __launch_bounds__(BLK) void trip_k(
    const float* __restrict__ Ang, const int* __restrict__ id3,
    const float* __restrict__ tab, const float* __restrict__ cst,
    float* __restrict__ out, int nT)
{
    __shared__ int   esh[BLK];       // 1 KB
    __shared__ float ysh[BLK * 8];   // 8 KB
    int tid = threadIdx.x;
    int base = blockIdx.x * BLK;
    int t = base + tid;
    bool ok = t < nT;
    int e = ok ? __builtin_nontemporal_load(id3 + t) : 0;
    float ang = ok ? __builtin_nontemporal_load(Ang + t) : 0.0f;
    esh[tid] = e * 24;   // row offset in f32x2 units (48 floats)

    float ct = glibc_cosf(ang);
    float P[NSPH];
    P[0] = 1.0f; P[1] = ct;
#pragma unroll
    for (int l = 1; l < NSPH - 1; ++l) {
        float t1 = __fmul_rn(__fmul_rn((float)(2 * l + 1), ct), P[l]);
        float t2 = __fmul_rn((float)l, P[l - 1]);
        P[l + 1] = __fdiv_rn(__fsub_rn(t1, t2), (float)(l + 1));
    }
#pragma unroll
    for (int l = 0; l < NSPH; ++l)
        ysh[tid * 8 + l] = __fmul_rn(cst[84 + l], P[l]);
    __syncthreads();

    const f32x2* tab2 = (const f32x2*)tab;
    f32x2* dst = (f32x2*)out + (long long)base * 21;
    int nv = nT - base; if (nv > BLK) nv = BLK;
    if (nv == BLK) {
#pragma unroll
        for (int it = 0; it < 21; ++it) {
            int i = tid + it * BLK;
            int r = i / 21, p = i - r * 21;
            f32x2 v = tab2[esh[r] + p];
            float ym = ysh[r * 8 + p / 3];
            f32x2 w;
            w.x = __fmul_rn(v.x, ym);
            w.y = __fmul_rn(v.y, ym);
            __builtin_nontemporal_store(w, dst + i);
        }
    } else {
        int nf2 = nv * 21; if (nf2 < 0) nf2 = 0;
        for (int i = tid; i < nf2; i += BLK) {
            int r = i / 21, p = i - r * 21;
            f32x2 v = tab2[esh[r] + p];
            float ym = ysh[r * 8 + p / 3];
            f32x2 w;
            w.x = __fmul_rn(v.x, ym);
            w.y = __fmul_rn(v.y, ym);
            __builtin_nontemporal_store(w, dst + i);
        }
    }
}

// ===== fallback: fused kernel (used only if ws too small) =====
__global__ __launch_bounds__(BLK) void sph_main(
    const float* __restrict__ D, const float* __restrict__ Ang,
    const int* __restrict__ id3, const float* __restrict__ cst,
    float* __restrict__ out, int nT)
{
    __shared__ float zf[42], bn[42], yn[7];
    __shared__ float stg[BLK * 42];
    int tid = threadIdx.x;
    if (tid < 42) { zf[tid] = cst[tid]; bn[tid] = cst[42 + tid]; }
    if (tid < 7)  { yn[tid] = cst[84 + tid]; }
    __syncthreads();
    int base = blockIdx.x * BLK;
    int t = base + tid;
    bool ok = t < nT;
    int e = ok ? id3[t] : 0;
    float Dv = D[e];
    float ang = ok ? Ang[t] : 0.0f;
    float d = __fmul_rn(Dv, 0.2f);
    float invd = __fdiv_rn(1.0f, d);
    float d2 = d * d, d4 = d2 * d2, d5 = d4 * d, d6 = d5 * d, d7 = d6 * d;
    float env = ((invd + (-28.0f) * d5) + 48.0f * d6) + (-21.0f) * d7;
    float u_d = (d < 1.0f) ? env : 0.0f;
    const float NC = (float)0.0894427190999916;
    float unc = __fmul_rn(u_d, NC);
    float ct = glibc_cosf(ang);
    float P[NSPH];
    P[0] = 1.0f; P[1] = ct;
#pragma unroll
    for (int l = 1; l < NSPH - 1; ++l) {
        float t1 = __fmul_rn(__fmul_rn((float)(2 * l + 1), ct), P[l]);
        float t2 = __fmul_rn((float)l, P[l - 1]);
        P[l + 1] = __fdiv_rn(__fsub_rn(t1, t2), (float)(l + 1));
    }
    float* row = &stg[tid * 42];
#pragma unroll
    for (int l = 0; l < NSPH; ++l) {
        float yPl = __fmul_rn(yn[l], P[l]);
        for (int n = 0; n < NRAD; ++n) {
            float z = zf[l * 6 + n];
            float x = __fmul_rn(d, z);
            float s, c;
            glibc_sincosf(x, s, c);
            float j = __fdiv_rn(s, x);
            if (l > 0) {
                float x2 = __fmul_rn(x, x);
                float j1 = __fsub_rn(__fdiv_rn(s, x2), __fdiv_rn(c, x));
                float jm1 = j, jc = j1;
                for (int kk = 1; kk < l; ++kk) {
                    float fk = __fdiv_rn((float)(2 * kk + 1), x);
                    float jn2 = __fsub_rn(__fmul_rn(fk, jc), jm1);
                    jm1 = jc; jc = jn2;
                }
                j = jc;
            }
            float re = __fmul_rn(unc, __fmul_rn(bn[l * 6 + n], j));
            row[l * 6 + n] = __fmul_rn(re, yPl);
        }
    }
    __syncthreads();
    int nv = nT - base; if (nv > BLK) nv = BLK;
    int nf2 = nv * 21;
    const float2* src = (const float2*)stg;
    float2* dst = (float2*)(out + (long long)base * 42);
    for (int i = tid; i < nf2; i += BLK) dst[i] = src[i];
}

extern "C" void kernel_launch(void* const* d_in, const int* in_sizes, int n_in,
                              void* d_out, int out_size, void* d_ws, size_t ws_size,
                              hipStream_t stream) {
    const float* D   = (const float*)d_in[0];
    const float* Ang = (const float*)d_in[1];
    const int*   id3 = (const int*)d_in[2];
    float* out = (float*)d_out;
    int nE = in_sizes[0];
    int nT = in_sizes[1];

    size_t tab_bytes = (size_t)nE * NE_PAD * sizeof(float);
    if (ws_size >= tab_bytes + 512) {
        float* tab = (float*)d_ws;
        float* cst = (float*)((char*)d_ws + tab_bytes);
        setup_k<<<1, 704, 0, stream>>>(cst);
        env_k<<<(nE + BLK - 1) / BLK, BLK, 0, stream>>>(D, tab, nE);
        int gA = (nE + EPB2 - 1) / EPB2;
        edge_k<<<gA, 448, 0, stream>>>(D, cst, tab, nE);
        int gB = (nT + BLK - 1) / BLK;
        trip_k<<<gB, BLK, 0, stream>>>(Ang, id3, tab, cst, out, nT);
    } else {
        float* cst = (float*)d_ws;   // 91 floats
        setup_k<<<1, 704, 0, stream>>>(cst);
        int grid = (nT + BLK - 1) / BLK;
        sph_main<<<grid, BLK, 0, stream>>>(D, Ang, id3, cst, out, nT);
    }
}

// Round 16
// 223.580 us; speedup vs baseline: 1.0723x; 1.0723x over previous
//
#include <hip/hip_runtime.h>
#include <math.h>
#include <stdint.h>

#define NSPH 7
#define NRAD 6
#define BLK  256
#define EPB2 10     // edges per edge_k block (448 threads = 7 waves x 10x6)
#define NE_PAD 48   // padded table row: 192 B (64B-aligned rows)

typedef float f32x2 __attribute__((ext_vector_type(2)));
typedef float f32x4 __attribute__((ext_vector_type(4)));

// ===== glibc sinf/cosf bit-exact replication =====
// (glibc sysdeps/ieee754/flt-32, baseline x86-64: f64 internals, NO fma)
// verified PASS rounds 3-15.
#define SC_HPI_INV 0x1.45F306DC9C883p+23   /* 2/pi * 2^24 */
#define SC_HPI     0x1.921FB54442D18p+0
#define SC_C0      (0x1p+0)
#define SC_C1      (-0x1.ffffffd0c621cp-2)
#define SC_C2      (0x1.55553e1068f19p-5)
#define SC_C3      (-0x1.6c087e89a359dp-10)
#define SC_C4      (0x1.99343027bf8c3p-16)
#define SC_S1      (-0x1.555545995a603p-3)
#define SC_S2      (0x1.1107605230bc4p-7)
#define SC_S3      (-0x1.994eb3774cf24p-13)

__device__ __forceinline__ unsigned abstop12(float x) {
    return (__float_as_uint(x) >> 20) & 0x7ffu;
}

__device__ __forceinline__ float sp_sin(double x, double x2) {
    double x3 = __dmul_rn(x, x2);
    double s1 = __dadd_rn(SC_S2, __dmul_rn(x2, SC_S3));
    double x7 = __dmul_rn(x3, x2);
    double s  = __dadd_rn(x, __dmul_rn(x3, SC_S1));
    return (float)__dadd_rn(s, __dmul_rn(x7, s1));
}

__device__ __forceinline__ float sp_cos(double x2, bool neg) {
    double c0 = neg ? -SC_C0 : SC_C0;
    double c1 = neg ? -SC_C1 : SC_C1;
    double c2 = neg ? -SC_C2 : SC_C2;
    double c3 = neg ? -SC_C3 : SC_C3;
    double c4 = neg ? -SC_C4 : SC_C4;
    double x4  = __dmul_rn(x2, x2);
    double c2v = __dadd_rn(c3, __dmul_rn(x2, c4));
    double c1v = __dadd_rn(c0, __dmul_rn(x2, c1));
    double x6  = __dmul_rn(x4, x2);
    double c   = __dadd_rn(c1v, __dmul_rn(x4, c2));
    return (float)__dadd_rn(c, __dmul_rn(x6, c2v));
}

// positive-coefficient cosine poly (sp_cos(x2,false))
__device__ __forceinline__ float sp_cos_pos(double x2) {
    double x4  = __dmul_rn(x2, x2);
    double c2v = __dadd_rn(SC_C3, __dmul_rn(x2, SC_C4));
    double c1v = __dadd_rn(SC_C0, __dmul_rn(x2, SC_C1));
    double x6  = __dmul_rn(x4, x2);
    double c   = __dadd_rn(c1v, __dmul_rn(x4, SC_C2));
    return (float)__dadd_rn(c, __dmul_rn(x6, c2v));
}

__device__ __forceinline__ double reduce_fast(double x, int* np) {
    double r = __dmul_rn(x, SC_HPI_INV);
    int n = (((int)r) + 0x800000) >> 24;
    *np = n;
    return __dsub_rn(x, __dmul_rn((double)n, SC_HPI));
}

__device__ __forceinline__ float glibc_cosf(float y) {
    unsigned at = abstop12(y);
    double x = (double)y;
    if (at < 0x3f4u) {
        if (at < 0x398u) return 1.0f;
        return sp_cos(__dmul_rn(x, x), false);
    }
    int n;
    double r = reduce_fast(x, &n);
    double s = ((n + 2) & 2) ? -1.0 : 1.0;
    bool neg = ((n + 1) & 2) != 0;
    int m = n ^ 1;
    double xs = __dmul_rn(r, s);
    double x2 = __dmul_rn(r, r);
    if ((m & 1) == 0) return sp_sin(xs, x2);
    return sp_cos(x2, neg);
}

// BOTH sinf(y) and cosf(y) with one reduce_fast; bit-identical to glibc calls.
__device__ __forceinline__ void glibc_sincosf(float y, float& so, float& co) {
    unsigned at = abstop12(y);
    double x = (double)y;
    if (at < 0x3f4u) {
        if (at < 0x398u) { so = y; co = 1.0f; return; }
        double x2 = __dmul_rn(x, x);
        so = sp_sin(x, x2);
        co = sp_cos(x2, false);
        return;
    }
    int n;
    double r = reduce_fast(x, &n);
    double x2 = __dmul_rn(r, r);
    double ss = ((n + 1) & 2) ? -1.0 : 1.0;
    double cs = ((n + 2) & 2) ? -1.0 : 1.0;
    bool sneg = (n & 2) != 0;
    bool cneg = ((n + 1) & 2) != 0;
    if ((n & 1) == 0) {
        so = sp_sin(__dmul_rn(r, ss), x2);
        co = sp_cos(x2, cneg);
    } else {
        so = sp_cos(x2, sneg);
        co = sp_sin(__dmul_rn(r, cs), x2);
    }
}

// Branch-free sincos for 2^-12 < x < 0.78125..117435 range (edge_k's x).
// Bit-identical to glibc_sincosf there (verified PASS rounds 10-15).
__device__ __forceinline__ void sincos_nr(float y, float& so, float& co) {
    int n;
    double r = reduce_fast((double)y, &n);
    double x2 = __dmul_rn(r, r);
    float sps = sp_sin(r, x2);      // sin(r) rounded to f32
    float spc = sp_cos_pos(x2);     // cos(r) rounded to f32
    unsigned sbit = (unsigned)(n & 2) << 30;          // sin negative iff n&2
    unsigned cbit = (unsigned)((n + 1) & 2) << 30;    // cos negative iff (n+1)&2
    bool odd = (n & 1) != 0;
    float sv = odd ? spc : sps;
    float cv = odd ? sps : spc;
    so = __uint_as_float(__float_as_uint(sv) ^ sbit);
    co = __uint_as_float(__float_as_uint(cv) ^ cbit);
}

// ===== fast f64 sincos for setup_k (0 < x < 64), abs err ~1e-16 ======
__device__ __forceinline__ void sincos_f64(double x, double& so, double& co) {
    const double TOPI   = 0.63661977236758138;      // 2/pi
    const double P2_H   = 1.5707963267341256e+00;   // pi/2 hi (33 bits)
    const double P2_M   = 6.0771005065061922e-11;   // pi/2 med
    const double P2_L   = 2.0222662487959506e-21;   // pi/2 lo
    const double RSHIFT = 6755399441055744.0;       // 1.5*2^52
    double fn = __dsub_rn(__fma_rn(x, TOPI, RSHIFT), RSHIFT);  // rne(x*2/pi)
    int n = (int)fn;
    double r = __fma_rn(-fn, P2_H, x);
    r = __fma_rn(-fn, P2_M, r);
    r = __fma_rn(-fn, P2_L, r);
    double r2 = __dmul_rn(r, r);
    double sp = -7.6471637318198165e-13;
    sp = __fma_rn(sp, r2,  1.6059043836821613e-10);
    sp = __fma_rn(sp, r2, -2.5052108385441720e-08);
    sp = __fma_rn(sp, r2,  2.7557319223985893e-06);
    sp = __fma_rn(sp, r2, -1.9841269841269841e-04);
    sp = __fma_rn(sp, r2,  8.3333333333333333e-03);
    sp = __fma_rn(sp, r2, -1.6666666666666667e-01);
    double ss = __fma_rn(__dmul_rn(sp, r2), r, r);
    double cp =  4.7794773323873853e-14;
    cp = __fma_rn(cp, r2, -1.1470745597729725e-11);
    cp = __fma_rn(cp, r2,  2.0876756987868099e-09);
    cp = __fma_rn(cp, r2, -2.7557319223985888e-07);
    cp = __fma_rn(cp, r2,  2.4801587301587302e-05);
    cp = __fma_rn(cp, r2, -1.3888888888888889e-03);
    cp = __fma_rn(cp, r2,  4.1666666666666666e-02);
    cp = __fma_rn(cp, r2, -5.0000000000000000e-01);
    double cc = __fma_rn(cp, r2, 1.0);
    bool odd = (n & 1) != 0;
    double sv = odd ? cc : ss;
    double cv = odd ? ss : cc;
    so = (n & 2) ? -sv : sv;
    co = ((n + 1) & 2) ? -cv : cv;
}

// ===== f64 spherical bessel, true divides (final zf/bn eval; r15 PASS) ====
__device__ __forceinline__ double jn_f64(double x, int n) {
    double s, c;
    sincos_f64(x, s, c);
    double j0 = s / x;
    if (n == 0) return j0;
    double j1 = s / (x * x) - c / x;
    double jm1 = j0, j = j1;
    for (int l = 1; l < n; ++l) {
        double t = (double)(2 * l + 1) / x * j - jm1;
        jm1 = j; j = t;
    }
    return j;
}

// Divide-free variant for bisection SIGN TESTS only: one divide (invx), then
// FMA-chain recurrence (serial depth ~8cyc/step vs ~100cyc/step with divides).
// Eval differs from jn_f64 by ~1 ulp -> root shift <=1e-15 (f32-cast safe).
__device__ __forceinline__ double jn_fast(double x, int n) {
    double s, c;
    sincos_f64(x, s, c);
    double invx = 1.0 / x;
    double j0 = __dmul_rn(s, invx);
    if (n == 0) return j0;
    double jc = __dmul_rn(__dsub_rn(j0, c), invx);   // (s/x - c)/x
    double jm1 = j0;
    for (int l = 1; l < n; ++l) {
        double fk = __dmul_rn((double)(2 * l + 1), invx);  // off critical path
        double t = __fma_rn(fk, jc, -jm1);
        jm1 = jc; jc = t;
    }
    return jc;
}

// cst layout (floats): [0..41] zf, [42..83] bnorm, [84..90] ynorm
__global__ __launch_bounds__(704) void setup_k(float* __restrict__ cst) {
    __shared__ double pts[13];
    __shared__ double roots[12];
    __shared__ double Z[NSPH][NRAD];
    const double PI = 3.141592653589793238462643383279502884;
    int tid = threadIdx.x, wv = tid >> 6, ln = tid & 63;
    if (tid < 12) pts[tid] = PI * (double)(tid + 1);
    __syncthreads();
    if (tid < NRAD) Z[0][tid] = pts[tid];
    for (int i = 1; i < NSPH; ++i) {
        int m = NRAD + NSPH - 1 - i;  // 12 - i
        if (wv < m) {
            double a = pts[wv], b = pts[wv + 1];
            for (int r = 0; r < 9; ++r) {
                double st = (b - a) * (1.0 / 63.0);
                double f = jn_fast(a + st * (double)ln, i);
                double f0 = __shfl(f, 0);
                unsigned long long bm = __ballot((ln > 0) && (f0 * f <= 0.0));
                int idx = bm ? (__ffsll((unsigned long long)bm) - 1) : 63;
                b = a + st * (double)idx;
                a = a + st * (double)(idx - 1);
            }
            if (ln == 0) roots[wv] = 0.5 * (a + b);
        }
        __syncthreads();
        if (tid < m) pts[tid] = roots[tid];
        if (tid < NRAD) Z[i][tid] = roots[tid];
        __syncthreads();
    }
    if (tid < NSPH * NRAD) {
        int l = tid / NRAD;
        double z = Z[l][tid % NRAD];
        cst[tid] = (float)z;
        double jp = jn_f64(z, l + 1);    // true-divide eval (r15-verified)
        cst[42 + tid] = (float)(1.0 / sqrt(0.5 * (jp * jp)));
    }
    if (tid < NSPH) {
        cst[84 + tid] = (float)sqrt((double)(2 * tid + 1) / (4.0 * PI));
    }
}

// ===== Phase A: rbf_env table; wave==l mapping; env inline =====
__global__ __launch_bounds__(448) void edge_k(
    const float* __restrict__ D, const float* __restrict__ cst,
    float* __restrict__ tab, int nE)
{
    int tid = threadIdx.x;
    int l    = tid >> 6;         // wave index == level (0..6)
    int ln   = tid & 63;
    int slot = ln / 6;           // 0..10 (slot 10 + lanes 60-63 idle)
    int n    = ln - slot * 6;
    long long e = (long long)blockIdx.x * EPB2 + slot;
    if (slot >= EPB2 || e >= (long long)nE) return;
    int k = l * 6 + n;

    // env inline (identical f32 ops as rounds 3-15 -> bit-exact)
    float d = __fmul_rn(D[e], 0.2f);
    float invd = __fdiv_rn(1.0f, d);
    float d2 = d * d, d4 = d2 * d2, d5 = d4 * d, d6 = d5 * d, d7 = d6 * d;
    float env = ((invd + (-28.0f) * d5) + 48.0f * d6) + (-21.0f) * d7;
    float u_d = (d < 1.0f) ? env : 0.0f;
    const float NC = (float)0.0894427190999916;  // 0.2**1.5
    float unc = __fmul_rn(u_d, NC);

    float z   = cst[k];
    float bnk = cst[42 + k];

    float x = __fmul_rn(d, z);   // x in (0.0063, 26.9): sincos_nr valid
    float s, c;
    sincos_nr(x, s, c);
    float j = __fdiv_rn(s, x);
    if (l > 0) {                 // wave-uniform
        float x2 = __fmul_rn(x, x);
        float j1 = __fsub_rn(__fdiv_rn(s, x2), __fdiv_rn(c, x));
        float jm1 = j, jc = j1;
        for (int kk = 1; kk < l; ++kk) {   // wave-uniform trip count
            float fk = __fdiv_rn((float)(2 * kk + 1), x);
            float jn2 = __fsub_rn(__fmul_rn(fk, jc), jm1);
            jm1 = jc; jc = jn2;
        }
        j = jc;
    }
    tab[e * NE_PAD + k] = __fmul_rn(unc, __fmul_rn(bnk, j));
}

// ===== Phase B: direct streamed gather->mul->NT store (r9-r15 structure) ====
__global__ __launch_bounds__(BLK) void trip_k(
    const float* __restrict__ Ang, const int* __restrict__ id3,
    const float* __restrict__ tab, const float* __restrict__ cst,
    float* __restrict__ out, int nT)
{
    __shared__ int   esh[BLK];       // 1 KB
    __shared__ float ysh[BLK * 8];   // 8 KB
    int tid = threadIdx.x;
    int base = blockIdx.x * BLK;
    int t = base + tid;
    bool ok = t < nT;
    int e = ok ? __builtin_nontemporal_load(id3 + t) : 0;
    float ang = ok ? __builtin_nontemporal_load(Ang + t) : 0.0f;
    esh[tid] = e * 24;   // row offset in f32x2 units (48 floats)

    float ct = glibc_cosf(ang);
    float P[NSPH];
    P[0] = 1.0f; P[1] = ct;
#pragma unroll
    for (int l = 1; l < NSPH - 1; ++l) {
        float t1 = __fmul_rn(__fmul_rn((float)(2 * l + 1), ct), P[l]);
        float t2 = __fmul_rn((float)l, P[l - 1]);
        P[l + 1] = __fdiv_rn(__fsub_rn(t1, t2), (float)(l + 1));
    }
#pragma unroll
    for (int l = 0; l < NSPH; ++l)
        ysh[tid * 8 + l] = __fmul_rn(cst[84 + l], P[l]);
    __syncthreads();

    const f32x2* tab2 = (const f32x2*)tab;
    f32x2* dst = (f32x2*)out + (long long)base * 21;
    int nv = nT - base; if (nv > BLK) nv = BLK;
    if (nv == BLK) {
#pragma unroll
        for (int it = 0; it < 21; ++it) {
            int i = tid + it * BLK;
            int r = i / 21, p = i - r * 21;
            f32x2 v = tab2[esh[r] + p];
            float ym = ysh[r * 8 + p / 3];
            f32x2 w;
            w.x = __fmul_rn(v.x, ym);
            w.y = __fmul_rn(v.y, ym);
            __builtin_nontemporal_store(w, dst + i);
        }
    } else {
        int nf2 = nv * 21; if (nf2 < 0) nf2 = 0;
        for (int i = tid; i < nf2; i += BLK) {
            int r = i / 21, p = i - r * 21;
            f32x2 v = tab2[esh[r] + p];
            float ym = ysh[r * 8 + p / 3];
            f32x2 w;
            w.x = __fmul_rn(v.x, ym);
            w.y = __fmul_rn(v.y, ym);
            __builtin_nontemporal_store(w, dst + i);
        }
    }
}

// ===== fallback: fused kernel (used only if ws too small) =====
__global__ __launch_bounds__(BLK) void sph_main(
    const float* __restrict__ D, const float* __restrict__ Ang,
    const int* __restrict__ id3, const float* __restrict__ cst,
    float* __restrict__ out, int nT)
{
    __shared__ float zf[42], bn[42], yn[7];
    __shared__ float stg[BLK * 42];
    int tid = threadIdx.x;
    if (tid < 42) { zf[tid] = cst[tid]; bn[tid] = cst[42 + tid]; }
    if (tid < 7)  { yn[tid] = cst[84 + tid]; }
    __syncthreads();
    int base = blockIdx.x * BLK;
    int t = base + tid;
    bool ok = t < nT;
    int e = ok ? id3[t] : 0;
    float Dv = D[e];
    float ang = ok ? Ang[t] : 0.0f;
    float d = __fmul_rn(Dv, 0.2f);
    float invd = __fdiv_rn(1.0f, d);
    float d2 = d * d, d4 = d2 * d2, d5 = d4 * d, d6 = d5 * d, d7 = d6 * d;
    float env = ((invd + (-28.0f) * d5) + 48.0f * d6) + (-21.0f) * d7;
    float u_d = (d < 1.0f) ? env : 0.0f;
    const float NC = (float)0.0894427190999916;
    float unc = __fmul_rn(u_d, NC);
    float ct = glibc_cosf(ang);
    float P[NSPH];
    P[0] = 1.0f; P[1] = ct;
#pragma unroll
    for (int l = 1; l < NSPH - 1; ++l) {
        float t1 = __fmul_rn(__fmul_rn((float)(2 * l + 1), ct), P[l]);
        float t2 = __fmul_rn((float)l, P[l - 1]);
        P[l + 1] = __fdiv_rn(__fsub_rn(t1, t2), (float)(l + 1));
    }
    float* row = &stg[tid * 42];
#pragma unroll
    for (int l = 0; l < NSPH; ++l) {
        float yPl = __fmul_rn(yn[l], P[l]);
        for (int n = 0; n < NRAD; ++n) {
            float z = zf[l * 6 + n];
            float x = __fmul_rn(d, z);
            float s, c;
            glibc_sincosf(x, s, c);
            float j = __fdiv_rn(s, x);
            if (l > 0) {
                float x2 = __fmul_rn(x, x);
                float j1 = __fsub_rn(__fdiv_rn(s, x2), __fdiv_rn(c, x));
                float jm1 = j, jc = j1;
                for (int kk = 1; kk < l; ++kk) {
                    float fk = __fdiv_rn((float)(2 * kk + 1), x);
                    float jn2 = __fsub_rn(__fmul_rn(fk, jc), jm1);
                    jm1 = jc; jc = jn2;
                }
                j = jc;
            }
            float re = __fmul_rn(unc, __fmul_rn(bn[l * 6 + n], j));
            row[l * 6 + n] = __fmul_rn(re, yPl);
        }
    }
    __syncthreads();
    int nv = nT - base; if (nv > BLK) nv = BLK;
    int nf2 = nv * 21;
    const float2* src = (const float2*)stg;
    float2* dst = (float2*)(out + (long long)base * 42);
    for (int i = tid; i < nf2; i += BLK) dst[i] = src[i];
}

extern "C" void kernel_launch(void* const* d_in, const int* in_sizes, int n_in,
                              void* d_out, int out_size, void* d_ws, size_t ws_size,
                              hipStream_t stream) {
    const float* D   = (const float*)d_in[0];
    const float* Ang = (const float*)d_in[1];
    const int*   id3 = (const int*)d_in[2];
    float* out = (float*)d_out;
    int nE = in_sizes[0];
    int nT = in_sizes[1];

    size_t tab_bytes = (size_t)nE * NE_PAD * sizeof(float);
    if (ws_size >= tab_bytes + 512) {
        float* tab = (float*)d_ws;
        float* cst = (float*)((char*)d_ws + tab_bytes);
        setup_k<<<1, 704, 0, stream>>>(cst);
        int gA = (nE + EPB2 - 1) / EPB2;
        edge_k<<<gA, 448, 0, stream>>>(D, cst, tab, nE);
        int gB = (nT + BLK - 1) / BLK;
        trip_k<<<gB, BLK, 0, stream>>>(Ang, id3, tab, cst, out, nT);
    } else {
        float* cst = (float*)d_ws;   // 91 floats
        setup_k<<<1, 704, 0, stream>>>(cst);
        int grid = (nT + BLK - 1) / BLK;
        sph_main<<<grid, BLK, 0, stream>>>(D, Ang, id3, cst, out, nT);
    }
}

// Round 17
// 217.618 us; speedup vs baseline: 1.1017x; 1.0274x over previous
//
#include <hip/hip_runtime.h>
#include <math.h>
#include <stdint.h>

#define NSPH 7
#define NRAD 6
#define BLK  256
#define EPB2 10     // edges per edge_k block (448 threads = 7 waves x 10x6)
#define NE_PAD 48   // padded table row: 192 B (64B-aligned rows)

typedef float f32x2 __attribute__((ext_vector_type(2)));
typedef float f32x4 __attribute__((ext_vector_type(4)));

// ===== glibc sinf/cosf bit-exact replication =====
// (glibc sysdeps/ieee754/flt-32, baseline x86-64: f64 internals, NO fma)
// verified PASS rounds 3-16.
#define SC_HPI_INV 0x1.45F306DC9C883p+23   /* 2/pi * 2^24 */
#define SC_HPI     0x1.921FB54442D18p+0
#define SC_C0      (0x1p+0)
#define SC_C1      (-0x1.ffffffd0c621cp-2)
#define SC_C2      (0x1.55553e1068f19p-5)
#define SC_C3      (-0x1.6c087e89a359dp-10)
#define SC_C4      (0x1.99343027bf8c3p-16)
#define SC_S1      (-0x1.555545995a603p-3)
#define SC_S2      (0x1.1107605230bc4p-7)
#define SC_S3      (-0x1.994eb3774cf24p-13)

__device__ __forceinline__ unsigned abstop12(float x) {
    return (__float_as_uint(x) >> 20) & 0x7ffu;
}

__device__ __forceinline__ float sp_sin(double x, double x2) {
    double x3 = __dmul_rn(x, x2);
    double s1 = __dadd_rn(SC_S2, __dmul_rn(x2, SC_S3));
    double x7 = __dmul_rn(x3, x2);
    double s  = __dadd_rn(x, __dmul_rn(x3, SC_S1));
    return (float)__dadd_rn(s, __dmul_rn(x7, s1));
}

__device__ __forceinline__ float sp_cos(double x2, bool neg) {
    double c0 = neg ? -SC_C0 : SC_C0;
    double c1 = neg ? -SC_C1 : SC_C1;
    double c2 = neg ? -SC_C2 : SC_C2;
    double c3 = neg ? -SC_C3 : SC_C3;
    double c4 = neg ? -SC_C4 : SC_C4;
    double x4  = __dmul_rn(x2, x2);
    double c2v = __dadd_rn(c3, __dmul_rn(x2, c4));
    double c1v = __dadd_rn(c0, __dmul_rn(x2, c1));
    double x6  = __dmul_rn(x4, x2);
    double c   = __dadd_rn(c1v, __dmul_rn(x4, c2));
    return (float)__dadd_rn(c, __dmul_rn(x6, c2v));
}

// positive-coefficient cosine poly (sp_cos(x2,false))
__device__ __forceinline__ float sp_cos_pos(double x2) {
    double x4  = __dmul_rn(x2, x2);
    double c2v = __dadd_rn(SC_C3, __dmul_rn(x2, SC_C4));
    double c1v = __dadd_rn(SC_C0, __dmul_rn(x2, SC_C1));
    double x6  = __dmul_rn(x4, x2);
    double c   = __dadd_rn(c1v, __dmul_rn(x4, SC_C2));
    return (float)__dadd_rn(c, __dmul_rn(x6, c2v));
}

__device__ __forceinline__ double reduce_fast(double x, int* np) {
    double r = __dmul_rn(x, SC_HPI_INV);
    int n = (((int)r) + 0x800000) >> 24;
    *np = n;
    return __dsub_rn(x, __dmul_rn((double)n, SC_HPI));
}

__device__ __forceinline__ float glibc_cosf(float y) {
    unsigned at = abstop12(y);
    double x = (double)y;
    if (at < 0x3f4u) {
        if (at < 0x398u) return 1.0f;
        return sp_cos(__dmul_rn(x, x), false);
    }
    int n;
    double r = reduce_fast(x, &n);
    double s = ((n + 2) & 2) ? -1.0 : 1.0;
    bool neg = ((n + 1) & 2) != 0;
    int m = n ^ 1;
    double xs = __dmul_rn(r, s);
    double x2 = __dmul_rn(r, r);
    if ((m & 1) == 0) return sp_sin(xs, x2);
    return sp_cos(x2, neg);
}

// BOTH sinf(y) and cosf(y) with one reduce_fast; bit-identical to glibc calls.
__device__ __forceinline__ void glibc_sincosf(float y, float& so, float& co) {
    unsigned at = abstop12(y);
    double x = (double)y;
    if (at < 0x3f4u) {
        if (at < 0x398u) { so = y; co = 1.0f; return; }
        double x2 = __dmul_rn(x, x);
        so = sp_sin(x, x2);
        co = sp_cos(x2, false);
        return;
    }
    int n;
    double r = reduce_fast(x, &n);
    double x2 = __dmul_rn(r, r);
    double ss = ((n + 1) & 2) ? -1.0 : 1.0;
    double cs = ((n + 2) & 2) ? -1.0 : 1.0;
    bool sneg = (n & 2) != 0;
    bool cneg = ((n + 1) & 2) != 0;
    if ((n & 1) == 0) {
        so = sp_sin(__dmul_rn(r, ss), x2);
        co = sp_cos(x2, cneg);
    } else {
        so = sp_cos(x2, sneg);
        co = sp_sin(__dmul_rn(r, cs), x2);
    }
}

// Branch-free sincos for 2^-12 < x < 0.78125..117435 range (edge_k's x).
// Bit-identical to glibc_sincosf there (verified PASS rounds 10-16).
__device__ __forceinline__ void sincos_nr(float y, float& so, float& co) {
    int n;
    double r = reduce_fast((double)y, &n);
    double x2 = __dmul_rn(r, r);
    float sps = sp_sin(r, x2);      // sin(r) rounded to f32
    float spc = sp_cos_pos(x2);     // cos(r) rounded to f32
    unsigned sbit = (unsigned)(n & 2) << 30;          // sin negative iff n&2
    unsigned cbit = (unsigned)((n + 1) & 2) << 30;    // cos negative iff (n+1)&2
    bool odd = (n & 1) != 0;
    float sv = odd ? spc : sps;
    float cv = odd ? sps : spc;
    so = __uint_as_float(__float_as_uint(sv) ^ sbit);
    co = __uint_as_float(__float_as_uint(cv) ^ cbit);
}

// ===== fast f64 sincos for setup_k (0 < x < 64), abs err ~1e-16 ======
__device__ __forceinline__ void sincos_f64(double x, double& so, double& co) {
    const double TOPI   = 0.63661977236758138;      // 2/pi
    const double P2_H   = 1.5707963267341256e+00;   // pi/2 hi (33 bits)
    const double P2_M   = 6.0771005065061922e-11;   // pi/2 med
    const double P2_L   = 2.0222662487959506e-21;   // pi/2 lo
    const double RSHIFT = 6755399441055744.0;       // 1.5*2^52
    double fn = __dsub_rn(__fma_rn(x, TOPI, RSHIFT), RSHIFT);  // rne(x*2/pi)
    int n = (int)fn;
    double r = __fma_rn(-fn, P2_H, x);
    r = __fma_rn(-fn, P2_M, r);
    r = __fma_rn(-fn, P2_L, r);
    double r2 = __dmul_rn(r, r);
    double sp = -7.6471637318198165e-13;
    sp = __fma_rn(sp, r2,  1.6059043836821613e-10);
    sp = __fma_rn(sp, r2, -2.5052108385441720e-08);
    sp = __fma_rn(sp, r2,  2.7557319223985893e-06);
    sp = __fma_rn(sp, r2, -1.9841269841269841e-04);
    sp = __fma_rn(sp, r2,  8.3333333333333333e-03);
    sp = __fma_rn(sp, r2, -1.6666666666666667e-01);
    double ss = __fma_rn(__dmul_rn(sp, r2), r, r);
    double cp =  4.7794773323873853e-14;
    cp = __fma_rn(cp, r2, -1.1470745597729725e-11);
    cp = __fma_rn(cp, r2,  2.0876756987868099e-09);
    cp = __fma_rn(cp, r2, -2.7557319223985888e-07);
    cp = __fma_rn(cp, r2,  2.4801587301587302e-05);
    cp = __fma_rn(cp, r2, -1.3888888888888889e-03);
    cp = __fma_rn(cp, r2,  4.1666666666666666e-02);
    cp = __fma_rn(cp, r2, -5.0000000000000000e-01);
    double cc = __fma_rn(cp, r2, 1.0);
    bool odd = (n & 1) != 0;
    double sv = odd ? cc : ss;
    double cv = odd ? ss : cc;
    so = (n & 2) ? -sv : sv;
    co = ((n + 1) & 2) ? -cv : cv;
}

// ===== f64 spherical bessel, true divides (final zf/bn eval; r15 PASS) ====
__device__ __forceinline__ double jn_f64(double x, int n) {
    double s, c;
    sincos_f64(x, s, c);
    double j0 = s / x;
    if (n == 0) return j0;
    double j1 = s / (x * x) - c / x;
    double jm1 = j0, j = j1;
    for (int l = 1; l < n; ++l) {
        double t = (double)(2 * l + 1) / x * j - jm1;
        jm1 = j; j = t;
    }
    return j;
}

// Divide-free fast eval for sign tests (r16-verified).
__device__ __forceinline__ double jn_fast(double x, int n) {
    double s, c;
    sincos_f64(x, s, c);
    double invx = 1.0 / x;
    double j0 = __dmul_rn(s, invx);
    if (n == 0) return j0;
    double jc = __dmul_rn(__dsub_rn(j0, c), invx);
    double jm1 = j0;
    for (int l = 1; l < n; ++l) {
        double fk = __dmul_rn((double)(2 * l + 1), invx);
        double t = __fma_rn(fk, jc, -jm1);
        jm1 = jc; jc = t;
    }
    return jc;
}

// Fast eval returning j_n AND j_{n-1} (for Newton: j_n' = j_{n-1} - (n+1)/x j_n)
__device__ __forceinline__ void jn_pair(double x, int n, double& jn_o,
                                        double& jnm1_o, double& invx_o) {
    double s, c;
    sincos_f64(x, s, c);
    double invx = 1.0 / x;
    double j0 = __dmul_rn(s, invx);
    double jc = __dmul_rn(__dsub_rn(j0, c), invx);   // j_1
    double jm1 = j0;
    for (int l = 1; l < n; ++l) {
        double fk = __dmul_rn((double)(2 * l + 1), invx);
        double t = __fma_rn(fk, jc, -jm1);
        jm1 = jc; jc = t;
    }
    jn_o = jc; jnm1_o = jm1; invx_o = invx;
}

// cst layout (floats): [0..41] zf, [42..83] bnorm, [84..90] ynorm
// 2 scan rounds (63-way) + 3 Newton iterations per level: root accurate to
// ~1e-15 rel (better than old 9-round bisection's 1e-12) -> f32 casts
// unchanged. Per-iter containment clamp guards a wild Newton step.
__global__ __launch_bounds__(704) void setup_k(float* __restrict__ cst) {
    __shared__ double pts[13];
    __shared__ double roots[12];
    __shared__ double Z[NSPH][NRAD];
    const double PI = 3.141592653589793238462643383279502884;
    int tid = threadIdx.x, wv = tid >> 6, ln = tid & 63;
    if (tid < 12) pts[tid] = PI * (double)(tid + 1);
    __syncthreads();
    if (tid < NRAD) Z[0][tid] = pts[tid];
    for (int i = 1; i < NSPH; ++i) {
        int m = NRAD + NSPH - 1 - i;  // 12 - i
        if (wv < m) {
            double a = pts[wv], b = pts[wv + 1];
            for (int r = 0; r < 2; ++r) {           // 2 x 63-way scan
                double st = (b - a) * (1.0 / 63.0);
                double f = jn_fast(a + st * (double)ln, i);
                double f0 = __shfl(f, 0);
                unsigned long long bm = __ballot((ln > 0) && (f0 * f <= 0.0));
                int idx = bm ? (__ffsll((unsigned long long)bm) - 1) : 63;
                b = a + st * (double)idx;
                a = a + st * (double)(idx - 1);
            }
            // interval width <= 3.7/63^2 ~ 9.3e-4; Newton x3 -> ~1e-15
            double x = 0.5 * (a + b);
            for (int it = 0; it < 3; ++it) {
                double jv, jm, ivx;
                jn_pair(x, i, jv, jm, ivx);
                double der = __fma_rn(-(double)(i + 1) * ivx, jv, jm);
                double xn = x - jv / der;
                x = (xn > a && xn < b) ? xn : 0.5 * (a + b);
            }
            if (ln == 0) roots[wv] = x;
        }
        __syncthreads();
        if (tid < m) pts[tid] = roots[tid];
        if (tid < NRAD) Z[i][tid] = roots[tid];
        __syncthreads();
    }
    if (tid < NSPH * NRAD) {
        int l = tid / NRAD;
        double z = Z[l][tid % NRAD];
        cst[tid] = (float)z;
        double jp = jn_f64(z, l + 1);    // true-divide eval (r15-verified)
        cst[42 + tid] = (float)(1.0 / sqrt(0.5 * (jp * jp)));
    }
    if (tid < NSPH) {
        cst[84 + tid] = (float)sqrt((double)(2 * tid + 1) / (4.0 * PI));
    }
}

// ===== Phase A: rbf_env table; wave==l mapping; env inline (r16) =====
__global__ __launch_bounds__(448) void edge_k(
    const float* __restrict__ D, const float* __restrict__ cst,
    float* __restrict__ tab, int nE)
{
    int tid = threadIdx.x;
    int l    = tid >> 6;         // wave index == level (0..6)
    int ln   = tid & 63;
    int slot = ln / 6;           // 0..10 (slot 10 + lanes 60-63 idle)
    int n    = ln - slot * 6;
    long long e = (long long)blockIdx.x * EPB2 + slot;
    if (slot >= EPB2 || e >= (long long)nE) return;
    int k = l * 6 + n;

    // env inline (identical f32 ops as rounds 3-16 -> bit-exact)
    float d = __fmul_rn(D[e], 0.2f);
    float invd = __fdiv_rn(1.0f, d);
    float d2 = d * d, d4 = d2 * d2, d5 = d4 * d, d6 = d5 * d, d7 = d6 * d;
    float env = ((invd + (-28.0f) * d5) + 48.0f * d6) + (-21.0f) * d7;
    float u_d = (d < 1.0f) ? env : 0.0f;
    const float NC = (float)0.0894427190999916;  // 0.2**1.5
    float unc = __fmul_rn(u_d, NC);

    float z   = cst[k];
    float bnk = cst[42 + k];

    float x = __fmul_rn(d, z);   // x in (0.0063, 26.9): sincos_nr valid
    float s, c;
    sincos_nr(x, s, c);
    float j = __fdiv_rn(s, x);
    if (l > 0) {                 // wave-uniform
        float x2 = __fmul_rn(x, x);
        float j1 = __fsub_rn(__fdiv_rn(s, x2), __fdiv_rn(c, x));
        float jm1 = j, jc = j1;
        for (int kk = 1; kk < l; ++kk) {   // wave-uniform trip count
            float fk = __fdiv_rn((float)(2 * kk + 1), x);
            float jn2 = __fsub_rn(__fmul_rn(fk, jc), jm1);
            jm1 = jc; jc = jn2;
        }
        j = jc;
    }
    tab[e * NE_PAD + k] = __fmul_rn(unc, __fmul_rn(bnk, j));
}

// ===== Phase B: direct streamed gather->mul->NT store (r9-r16 structure) ====
__global__ __launch_bounds__(BLK) void trip_k(
    const float* __restrict__ Ang, const int* __restrict__ id3,
    const float* __restrict__ tab, const float* __restrict__ cst,
    float* __restrict__ out, int nT)
{
    __shared__ int   esh[BLK];       // 1 KB
    __shared__ float ysh[BLK * 8];   // 8 KB
    int tid = threadIdx.x;
    int base = blockIdx.x * BLK;
    int t = base + tid;
    bool ok = t < nT;
    int e = ok ? __builtin_nontemporal_load(id3 + t) : 0;
    float ang = ok ? __builtin_nontemporal_load(Ang + t) : 0.0f;
    esh[tid] = e * 24;   // row offset in f32x2 units (48 floats)

    float ct = glibc_cosf(ang);
    float P[NSPH];
    P[0] = 1.0f; P[1] = ct;
#pragma unroll
    for (int l = 1; l < NSPH - 1; ++l) {
        float t1 = __fmul_rn(__fmul_rn((float)(2 * l + 1), ct), P[l]);
        float t2 = __fmul_rn((float)l, P[l - 1]);
        P[l + 1] = __fdiv_rn(__fsub_rn(t1, t2), (float)(l + 1));
    }
#pragma unroll
    for (int l = 0; l < NSPH; ++l)
        ysh[tid * 8 + l] = __fmul_rn(cst[84 + l], P[l]);
    __syncthreads();

    const f32x2* tab2 = (const f32x2*)tab;
    f32x2* dst = (f32x2*)out + (long long)base * 21;
    int nv = nT - base; if (nv > BLK) nv = BLK;
    if (nv == BLK) {
#pragma unroll
        for (int it = 0; it < 21; ++it) {
            int i = tid + it * BLK;
            int r = i / 21, p = i - r * 21;
            f32x2 v = tab2[esh[r] + p];
            float ym = ysh[r * 8 + p / 3];
            f32x2 w;
            w.x = __fmul_rn(v.x, ym);
            w.y = __fmul_rn(v.y, ym);
            __builtin_nontemporal_store(w, dst + i);
        }
    } else {
        int nf2 = nv * 21; if (nf2 < 0) nf2 = 0;
        for (int i = tid; i < nf2; i += BLK) {
            int r = i / 21, p = i - r * 21;
            f32x2 v = tab2[esh[r] + p];
            float ym = ysh[r * 8 + p / 3];
            f32x2 w;
            w.x = __fmul_rn(v.x, ym);
            w.y = __fmul_rn(v.y, ym);
            __builtin_nontemporal_store(w, dst + i);
        }
    }
}

// ===== fallback: fused kernel (used only if ws too small) =====
__global__ __launch_bounds__(BLK) void sph_main(
    const float* __restrict__ D, const float* __restrict__ Ang,
    const int* __restrict__ id3, const float* __restrict__ cst,
    float* __restrict__ out, int nT)
{
    __shared__ float zf[42], bn[42], yn[7];
    __shared__ float stg[BLK * 42];
    int tid = threadIdx.x;
    if (tid < 42) { zf[tid] = cst[tid]; bn[tid] = cst[42 + tid]; }
    if (tid < 7)  { yn[tid] = cst[84 + tid]; }
    __syncthreads();
    int base = blockIdx.x * BLK;
    int t = base + tid;
    bool ok = t < nT;
    int e = ok ? id3[t] : 0;
    float Dv = D[e];
    float ang = ok ? Ang[t] : 0.0f;
    float d = __fmul_rn(Dv, 0.2f);
    float invd = __fdiv_rn(1.0f, d);
    float d2 = d * d, d4 = d2 * d2, d5 = d4 * d, d6 = d5 * d, d7 = d6 * d;
    float env = ((invd + (-28.0f) * d5) + 48.0f * d6) + (-21.0f) * d7;
    float u_d = (d < 1.0f) ? env : 0.0f;
    const float NC = (float)0.0894427190999916;
    float unc = __fmul_rn(u_d, NC);
    float ct = glibc_cosf(ang);
    float P[NSPH];
    P[0] = 1.0f; P[1] = ct;
#pragma unroll
    for (int l = 1; l < NSPH - 1; ++l) {
        float t1 = __fmul_rn(__fmul_rn((float)(2 * l + 1), ct), P[l]);
        float t2 = __fmul_rn((float)l, P[l - 1]);
        P[l + 1] = __fdiv_rn(__fsub_rn(t1, t2), (float)(l + 1));
    }
    float* row = &stg[tid * 42];
#pragma unroll
    for (int l = 0; l < NSPH; ++l) {
        float yPl = __fmul_rn(yn[l], P[l]);
        for (int n = 0; n < NRAD; ++n) {
            float z = zf[l * 6 + n];
            float x = __fmul_rn(d, z);
            float s, c;
            glibc_sincosf(x, s, c);
            float j = __fdiv_rn(s, x);
            if (l > 0) {
                float x2 = __fmul_rn(x, x);
                float j1 = __fsub_rn(__fdiv_rn(s, x2), __fdiv_rn(c, x));
                float jm1 = j, jc = j1;
                for (int kk = 1; kk < l; ++kk) {
                    float fk = __fdiv_rn((float)(2 * kk + 1), x);
                    float jn2 = __fsub_rn(__fmul_rn(fk, jc), jm1);
                    jm1 = jc; jc = jn2;
                }
                j = jc;
            }
            float re = __fmul_rn(unc, __fmul_rn(bn[l * 6 + n], j));
            row[l * 6 + n] = __fmul_rn(re, yPl);
        }
    }
    __syncthreads();
    int nv = nT - base; if (nv > BLK) nv = BLK;
    int nf2 = nv * 21;
    const float2* src = (const float2*)stg;
    float2* dst = (float2*)(out + (long long)base * 42);
    for (int i = tid; i < nf2; i += BLK) dst[i] = src[i];
}

extern "C" void kernel_launch(void* const* d_in, const int* in_sizes, int n_in,
                              void* d_out, int out_size, void* d_ws, size_t ws_size,
                              hipStream_t stream) {
    const float* D   = (const float*)d_in[0];
    const float* Ang = (const float*)d_in[1];
    const int*   id3 = (const int*)d_in[2];
    float* out = (float*)d_out;
    int nE = in_sizes[0];
    int nT = in_sizes[1];

    size_t tab_bytes = (size_t)nE * NE_PAD * sizeof(float);
    if (ws_size >= tab_bytes + 512) {
        float* tab = (float*)d_ws;
        float* cst = (float*)((char*)d_ws + tab_bytes);
        setup_k<<<1, 704, 0, stream>>>(cst);
        int gA = (nE + EPB2 - 1) / EPB2;
        edge_k<<<gA, 448, 0, stream>>>(D, cst, tab, nE);
        int gB = (nT + BLK - 1) / BLK;
        trip_k<<<gB, BLK, 0, stream>>>(Ang, id3, tab, cst, out, nT);
    } else {
        float* cst = (float*)d_ws;   // 91 floats
        setup_k<<<1, 704, 0, stream>>>(cst);
        int grid = (nT + BLK - 1) / BLK;
        sph_main<<<grid, BLK, 0, stream>>>(D, Ang, id3, cst, out, nT);
    }
}

// Round 18
// 216.560 us; speedup vs baseline: 1.1071x; 1.0049x over previous
//
#include <hip/hip_runtime.h>
#include <math.h>
#include <stdint.h>

#define NSPH 7
#define NRAD 6
#define BLK  256
#define EPB2 10     // edges per edge_k block (448 threads = 7 waves x 10x6)
#define NE_PAD 48   // padded table row: 192 B (64B-aligned rows)

typedef float f32x2 __attribute__((ext_vector_type(2)));
typedef float f32x4 __attribute__((ext_vector_type(4)));

// ===== glibc sinf/cosf bit-exact replication =====
// (glibc sysdeps/ieee754/flt-32, baseline x86-64: f64 internals, NO fma)
// verified PASS rounds 3-17.
#define SC_HPI_INV 0x1.45F306DC9C883p+23   /* 2/pi * 2^24 */
#define SC_HPI     0x1.921FB54442D18p+0
#define SC_C0      (0x1p+0)
#define SC_C1      (-0x1.ffffffd0c621cp-2)
#define SC_C2      (0x1.55553e1068f19p-5)
#define SC_C3      (-0x1.6c087e89a359dp-10)
#define SC_C4      (0x1.99343027bf8c3p-16)
#define SC_S1      (-0x1.555545995a603p-3)
#define SC_S2      (0x1.1107605230bc4p-7)
#define SC_S3      (-0x1.994eb3774cf24p-13)

__device__ __forceinline__ unsigned abstop12(float x) {
    return (__float_as_uint(x) >> 20) & 0x7ffu;
}

__device__ __forceinline__ float sp_sin(double x, double x2) {
    double x3 = __dmul_rn(x, x2);
    double s1 = __dadd_rn(SC_S2, __dmul_rn(x2, SC_S3));
    double x7 = __dmul_rn(x3, x2);
    double s  = __dadd_rn(x, __dmul_rn(x3, SC_S1));
    return (float)__dadd_rn(s, __dmul_rn(x7, s1));
}

__device__ __forceinline__ float sp_cos(double x2, bool neg) {
    double c0 = neg ? -SC_C0 : SC_C0;
    double c1 = neg ? -SC_C1 : SC_C1;
    double c2 = neg ? -SC_C2 : SC_C2;
    double c3 = neg ? -SC_C3 : SC_C3;
    double c4 = neg ? -SC_C4 : SC_C4;
    double x4  = __dmul_rn(x2, x2);
    double c2v = __dadd_rn(c3, __dmul_rn(x2, c4));
    double c1v = __dadd_rn(c0, __dmul_rn(x2, c1));
    double x6  = __dmul_rn(x4, x2);
    double c   = __dadd_rn(c1v, __dmul_rn(x4, c2));
    return (float)__dadd_rn(c, __dmul_rn(x6, c2v));
}

// positive-coefficient cosine poly (sp_cos(x2,false))
__device__ __forceinline__ float sp_cos_pos(double x2) {
    double x4  = __dmul_rn(x2, x2);
    double c2v = __dadd_rn(SC_C3, __dmul_rn(x2, SC_C4));
    double c1v = __dadd_rn(SC_C0, __dmul_rn(x2, SC_C1));
    double x6  = __dmul_rn(x4, x2);
    double c   = __dadd_rn(c1v, __dmul_rn(x4, SC_C2));
    return (float)__dadd_rn(c, __dmul_rn(x6, c2v));
}

__device__ __forceinline__ double reduce_fast(double x, int* np) {
    double r = __dmul_rn(x, SC_HPI_INV);
    int n = (((int)r) + 0x800000) >> 24;
    *np = n;
    return __dsub_rn(x, __dmul_rn((double)n, SC_HPI));
}

__device__ __forceinline__ float glibc_cosf(float y) {
    unsigned at = abstop12(y);
    double x = (double)y;
    if (at < 0x3f4u) {
        if (at < 0x398u) return 1.0f;
        return sp_cos(__dmul_rn(x, x), false);
    }
    int n;
    double r = reduce_fast(x, &n);
    double s = ((n + 2) & 2) ? -1.0 : 1.0;
    bool neg = ((n + 1) & 2) != 0;
    int m = n ^ 1;
    double xs = __dmul_rn(r, s);
    double x2 = __dmul_rn(r, r);
    if ((m & 1) == 0) return sp_sin(xs, x2);
    return sp_cos(x2, neg);
}

// BOTH sinf(y) and cosf(y) with one reduce_fast; bit-identical to glibc calls.
__device__ __forceinline__ void glibc_sincosf(float y, float& so, float& co) {
    unsigned at = abstop12(y);
    double x = (double)y;
    if (at < 0x3f4u) {
        if (at < 0x398u) { so = y; co = 1.0f; return; }
        double x2 = __dmul_rn(x, x);
        so = sp_sin(x, x2);
        co = sp_cos(x2, false);
        return;
    }
    int n;
    double r = reduce_fast(x, &n);
    double x2 = __dmul_rn(r, r);
    double ss = ((n + 1) & 2) ? -1.0 : 1.0;
    double cs = ((n + 2) & 2) ? -1.0 : 1.0;
    bool sneg = (n & 2) != 0;
    bool cneg = ((n + 1) & 2) != 0;
    if ((n & 1) == 0) {
        so = sp_sin(__dmul_rn(r, ss), x2);
        co = sp_cos(x2, cneg);
    } else {
        so = sp_cos(x2, sneg);
        co = sp_sin(__dmul_rn(r, cs), x2);
    }
}

// Branch-free sincos for 2^-12 < x < 0.78125..117435 range (edge_k's x).
// Bit-identical to glibc_sincosf there (verified PASS rounds 10-17).
__device__ __forceinline__ void sincos_nr(float y, float& so, float& co) {
    int n;
    double r = reduce_fast((double)y, &n);
    double x2 = __dmul_rn(r, r);
    float sps = sp_sin(r, x2);      // sin(r) rounded to f32
    float spc = sp_cos_pos(x2);     // cos(r) rounded to f32
    unsigned sbit = (unsigned)(n & 2) << 30;          // sin negative iff n&2
    unsigned cbit = (unsigned)((n + 1) & 2) << 30;    // cos negative iff (n+1)&2
    bool odd = (n & 1) != 0;
    float sv = odd ? spc : sps;
    float cv = odd ? sps : spc;
    so = __uint_as_float(__float_as_uint(sv) ^ sbit);
    co = __uint_as_float(__float_as_uint(cv) ^ cbit);
}

// ===== fast f64 sincos for setup_k (0 < x < 64), abs err ~1e-16 ======
__device__ __forceinline__ void sincos_f64(double x, double& so, double& co) {
    const double TOPI   = 0.63661977236758138;      // 2/pi
    const double P2_H   = 1.5707963267341256e+00;   // pi/2 hi (33 bits)
    const double P2_M   = 6.0771005065061922e-11;   // pi/2 med
    const double P2_L   = 2.0222662487959506e-21;   // pi/2 lo
    const double RSHIFT = 6755399441055744.0;       // 1.5*2^52
    double fn = __dsub_rn(__fma_rn(x, TOPI, RSHIFT), RSHIFT);  // rne(x*2/pi)
    int n = (int)fn;
    double r = __fma_rn(-fn, P2_H, x);
    r = __fma_rn(-fn, P2_M, r);
    r = __fma_rn(-fn, P2_L, r);
    double r2 = __dmul_rn(r, r);
    double sp = -7.6471637318198165e-13;
    sp = __fma_rn(sp, r2,  1.6059043836821613e-10);
    sp = __fma_rn(sp, r2, -2.5052108385441720e-08);
    sp = __fma_rn(sp, r2,  2.7557319223985893e-06);
    sp = __fma_rn(sp, r2, -1.9841269841269841e-04);
    sp = __fma_rn(sp, r2,  8.3333333333333333e-03);
    sp = __fma_rn(sp, r2, -1.6666666666666667e-01);
    double ss = __fma_rn(__dmul_rn(sp, r2), r, r);
    double cp =  4.7794773323873853e-14;
    cp = __fma_rn(cp, r2, -1.1470745597729725e-11);
    cp = __fma_rn(cp, r2,  2.0876756987868099e-09);
    cp = __fma_rn(cp, r2, -2.7557319223985888e-07);
    cp = __fma_rn(cp, r2,  2.4801587301587302e-05);
    cp = __fma_rn(cp, r2, -1.3888888888888889e-03);
    cp = __fma_rn(cp, r2,  4.1666666666666666e-02);
    cp = __fma_rn(cp, r2, -5.0000000000000000e-01);
    double cc = __fma_rn(cp, r2, 1.0);
    bool odd = (n & 1) != 0;
    double sv = odd ? cc : ss;
    double cv = odd ? ss : cc;
    so = (n & 2) ? -sv : sv;
    co = ((n + 1) & 2) ? -cv : cv;
}

// ===== f64 spherical bessel, true divides (final zf/bn eval; r15 PASS) ====
__device__ __forceinline__ double jn_f64(double x, int n) {
    double s, c;
    sincos_f64(x, s, c);
    double j0 = s / x;
    if (n == 0) return j0;
    double j1 = s / (x * x) - c / x;
    double jm1 = j0, j = j1;
    for (int l = 1; l < n; ++l) {
        double t = (double)(2 * l + 1) / x * j - jm1;
        jm1 = j; j = t;
    }
    return j;
}

// Divide-free fast eval for sign tests (r16-verified).
__device__ __forceinline__ double jn_fast(double x, int n) {
    double s, c;
    sincos_f64(x, s, c);
    double invx = 1.0 / x;
    double j0 = __dmul_rn(s, invx);
    if (n == 0) return j0;
    double jc = __dmul_rn(__dsub_rn(j0, c), invx);
    double jm1 = j0;
    for (int l = 1; l < n; ++l) {
        double fk = __dmul_rn((double)(2 * l + 1), invx);
        double t = __fma_rn(fk, jc, -jm1);
        jm1 = jc; jc = t;
    }
    return jc;
}

// Fast eval returning j_n AND j_{n-1} (for Newton: j_n' = j_{n-1} - (n+1)/x j_n)
__device__ __forceinline__ void jn_pair(double x, int n, double& jn_o,
                                        double& jnm1_o, double& invx_o) {
    double s, c;
    sincos_f64(x, s, c);
    double invx = 1.0 / x;
    double j0 = __dmul_rn(s, invx);
    double jc = __dmul_rn(__dsub_rn(j0, c), invx);   // j_1
    double jm1 = j0;
    for (int l = 1; l < n; ++l) {
        double fk = __dmul_rn((double)(2 * l + 1), invx);
        double t = __fma_rn(fk, jc, -jm1);
        jm1 = jc; jc = t;
    }
    jn_o = jc; jnm1_o = jm1; invx_o = invx;
}

// cst layout (floats): [0..41] zf, [42..83] bnorm, [84..90] ynorm
// 2 scan rounds (63-way) + 3 Newton iterations per level (r17-verified).
__global__ __launch_bounds__(704) void setup_k(float* __restrict__ cst) {
    __shared__ double pts[13];
    __shared__ double roots[12];
    __shared__ double Z[NSPH][NRAD];
    const double PI = 3.141592653589793238462643383279502884;
    int tid = threadIdx.x, wv = tid >> 6, ln = tid & 63;
    if (tid < 12) pts[tid] = PI * (double)(tid + 1);
    __syncthreads();
    if (tid < NRAD) Z[0][tid] = pts[tid];
    for (int i = 1; i < NSPH; ++i) {
        int m = NRAD + NSPH - 1 - i;  // 12 - i
        if (wv < m) {
            double a = pts[wv], b = pts[wv + 1];
            for (int r = 0; r < 2; ++r) {           // 2 x 63-way scan
                double st = (b - a) * (1.0 / 63.0);
                double f = jn_fast(a + st * (double)ln, i);
                double f0 = __shfl(f, 0);
                unsigned long long bm = __ballot((ln > 0) && (f0 * f <= 0.0));
                int idx = bm ? (__ffsll((unsigned long long)bm) - 1) : 63;
                b = a + st * (double)idx;
                a = a + st * (double)(idx - 1);
            }
            // interval width <= 3.7/63^2 ~ 9.3e-4; Newton x3 -> ~1e-15
            double x = 0.5 * (a + b);
            for (int it = 0; it < 3; ++it) {
                double jv, jm, ivx;
                jn_pair(x, i, jv, jm, ivx);
                double der = __fma_rn(-(double)(i + 1) * ivx, jv, jm);
                double xn = x - jv / der;
                x = (xn > a && xn < b) ? xn : 0.5 * (a + b);
            }
            if (ln == 0) roots[wv] = x;
        }
        __syncthreads();
        if (tid < m) pts[tid] = roots[tid];
        if (tid < NRAD) Z[i][tid] = roots[tid];
        __syncthreads();
    }
    if (tid < NSPH * NRAD) {
        int l = tid / NRAD;
        double z = Z[l][tid % NRAD];
        cst[tid] = (float)z;
        double jp = jn_f64(z, l + 1);    // true-divide eval (r15-verified)
        cst[42 + tid] = (float)(1.0 / sqrt(0.5 * (jp * jp)));
    }
    if (tid < NSPH) {
        cst[84 + tid] = (float)sqrt((double)(2 * tid + 1) / (4.0 * PI));
    }
}

// ===== Phase A: rbf_env table; wave==l mapping; env inline (r16/r17) =====
__global__ __launch_bounds__(448) void edge_k(
    const float* __restrict__ D, const float* __restrict__ cst,
    float* __restrict__ tab, int nE)
{
    int tid = threadIdx.x;
    int l    = tid >> 6;         // wave index == level (0..6)
    int ln   = tid & 63;
    int slot = ln / 6;           // 0..10 (slot 10 + lanes 60-63 idle)
    int n    = ln - slot * 6;
    long long e = (long long)blockIdx.x * EPB2 + slot;
    if (slot >= EPB2 || e >= (long long)nE) return;
    int k = l * 6 + n;

    // env inline (identical f32 ops as rounds 3-17 -> bit-exact)
    float d = __fmul_rn(D[e], 0.2f);
    float invd = __fdiv_rn(1.0f, d);
    float d2 = d * d, d4 = d2 * d2, d5 = d4 * d, d6 = d5 * d, d7 = d6 * d;
    float env = ((invd + (-28.0f) * d5) + 48.0f * d6) + (-21.0f) * d7;
    float u_d = (d < 1.0f) ? env : 0.0f;
    const float NC = (float)0.0894427190999916;  // 0.2**1.5
    float unc = __fmul_rn(u_d, NC);

    float z   = cst[k];
    float bnk = cst[42 + k];

    float x = __fmul_rn(d, z);   // x in (0.0063, 26.9): sincos_nr valid
    float s, c;
    sincos_nr(x, s, c);
    float j = __fdiv_rn(s, x);
    if (l > 0) {                 // wave-uniform
        float x2 = __fmul_rn(x, x);
        float j1 = __fsub_rn(__fdiv_rn(s, x2), __fdiv_rn(c, x));
        float jm1 = j, jc = j1;
        for (int kk = 1; kk < l; ++kk) {   // wave-uniform trip count
            float fk = __fdiv_rn((float)(2 * kk + 1), x);
            float jn2 = __fsub_rn(__fmul_rn(fk, jc), jm1);
            jm1 = jc; jc = jn2;
        }
        j = jc;
    }
    tab[e * NE_PAD + k] = __fmul_rn(unc, __fmul_rn(bnk, j));
}

// ===== Phase B: gather with forced 21-deep MLP, then mul+NT store =====
// Same loads / same single __fmul_rn / same store addresses as r9-r17
// (bit-identical output); only the ISSUE ORDER changes: all 21 independent
// gathers are forced into registers before first use (v[21] live across
// the split), raising per-thread loads-in-flight ~3 -> 21.
__global__ __launch_bounds__(BLK) void trip_k(
    const float* __restrict__ Ang, const int* __restrict__ id3,
    const float* __restrict__ tab, const float* __restrict__ cst,
    float* __restrict__ out, int nT)
{
    __shared__ int   esh[BLK];       // 1 KB
    __shared__ float ysh[BLK * 8];   // 8 KB
    int tid = threadIdx.x;
    int base = blockIdx.x * BLK;
    int t = base + tid;
    bool ok = t < nT;
    int e = ok ? __builtin_nontemporal_load(id3 + t) : 0;
    float ang = ok ? __builtin_nontemporal_load(Ang + t) : 0.0f;
    esh[tid] = e * 24;   // row offset in f32x2 units (48 floats)

    float ct = glibc_cosf(ang);
    float P[NSPH];
    P[0] = 1.0f; P[1] = ct;
#pragma unroll
    for (int l = 1; l < NSPH - 1; ++l) {
        float t1 = __fmul_rn(__fmul_rn((float)(2 * l + 1), ct), P[l]);
        float t2 = __fmul_rn((float)l, P[l - 1]);
        P[l + 1] = __fdiv_rn(__fsub_rn(t1, t2), (float)(l + 1));
    }
#pragma unroll
    for (int l = 0; l < NSPH; ++l)
        ysh[tid * 8 + l] = __fmul_rn(cst[84 + l], P[l]);
    __syncthreads();

    const f32x2* tab2 = (const f32x2*)tab;
    f32x2* dst = (f32x2*)out + (long long)base * 21;
    int nv = nT - base; if (nv > BLK) nv = BLK;
    if (nv == BLK) {
        f32x2 v[21];
#pragma unroll
        for (int it = 0; it < 21; ++it) {       // issue all 21 gathers
            int i = tid + it * BLK;
            int r = i / 21, p = i - r * 21;
            v[it] = tab2[esh[r] + p];
        }
#pragma unroll
        for (int it = 0; it < 21; ++it) {       // consume + store
            int i = tid + it * BLK;
            int r = i / 21, p = i - r * 21;
            float ym = ysh[r * 8 + p / 3];
            f32x2 w;
            w.x = __fmul_rn(v[it].x, ym);
            w.y = __fmul_rn(v[it].y, ym);
            __builtin_nontemporal_store(w, dst + i);
        }
    } else {
        int nf2 = nv * 21; if (nf2 < 0) nf2 = 0;
        for (int i = tid; i < nf2; i += BLK) {
            int r = i / 21, p = i - r * 21;
            f32x2 v = tab2[esh[r] + p];
            float ym = ysh[r * 8 + p / 3];
            f32x2 w;
            w.x = __fmul_rn(v.x, ym);
            w.y = __fmul_rn(v.y, ym);
            __builtin_nontemporal_store(w, dst + i);
        }
    }
}

// ===== fallback: fused kernel (used only if ws too small) =====
__global__ __launch_bounds__(BLK) void sph_main(
    const float* __restrict__ D, const float* __restrict__ Ang,
    const int* __restrict__ id3, const float* __restrict__ cst,
    float* __restrict__ out, int nT)
{
    __shared__ float zf[42], bn[42], yn[7];
    __shared__ float stg[BLK * 42];
    int tid = threadIdx.x;
    if (tid < 42) { zf[tid] = cst[tid]; bn[tid] = cst[42 + tid]; }
    if (tid < 7)  { yn[tid] = cst[84 + tid]; }
    __syncthreads();
    int base = blockIdx.x * BLK;
    int t = base + tid;
    bool ok = t < nT;
    int e = ok ? id3[t] : 0;
    float Dv = D[e];
    float ang = ok ? Ang[t] : 0.0f;
    float d = __fmul_rn(Dv, 0.2f);
    float invd = __fdiv_rn(1.0f, d);
    float d2 = d * d, d4 = d2 * d2, d5 = d4 * d, d6 = d5 * d, d7 = d6 * d;
    float env = ((invd + (-28.0f) * d5) + 48.0f * d6) + (-21.0f) * d7;
    float u_d = (d < 1.0f) ? env : 0.0f;
    const float NC = (float)0.0894427190999916;
    float unc = __fmul_rn(u_d, NC);
    float ct = glibc_cosf(ang);
    float P[NSPH];
    P[0] = 1.0f; P[1] = ct;
#pragma unroll
    for (int l = 1; l < NSPH - 1; ++l) {
        float t1 = __fmul_rn(__fmul_rn((float)(2 * l + 1), ct), P[l]);
        float t2 = __fmul_rn((float)l, P[l - 1]);
        P[l + 1] = __fdiv_rn(__fsub_rn(t1, t2), (float)(l + 1));
    }
    float* row = &stg[tid * 42];
#pragma unroll
    for (int l = 0; l < NSPH; ++l) {
        float yPl = __fmul_rn(yn[l], P[l]);
        for (int n = 0; n < NRAD; ++n) {
            float z = zf[l * 6 + n];
            float x = __fmul_rn(d, z);
            float s, c;
            glibc_sincosf(x, s, c);
            float j = __fdiv_rn(s, x);
            if (l > 0) {
                float x2 = __fmul_rn(x, x);
                float j1 = __fsub_rn(__fdiv_rn(s, x2), __fdiv_rn(c, x));
                float jm1 = j, jc = j1;
                for (int kk = 1; kk < l; ++kk) {
                    float fk = __fdiv_rn((float)(2 * kk + 1), x);
                    float jn2 = __fsub_rn(__fmul_rn(fk, jc), jm1);
                    jm1 = jc; jc = jn2;
                }
                j = jc;
            }
            float re = __fmul_rn(unc, __fmul_rn(bn[l * 6 + n], j));
            row[l * 6 + n] = __fmul_rn(re, yPl);
        }
    }
    __syncthreads();
    int nv = nT - base; if (nv > BLK) nv = BLK;
    int nf2 = nv * 21;
    const float2* src = (const float2*)stg;
    float2* dst = (float2*)(out + (long long)base * 42);
    for (int i = tid; i < nf2; i += BLK) dst[i] = src[i];
}

extern "C" void kernel_launch(void* const* d_in, const int* in_sizes, int n_in,
                              void* d_out, int out_size, void* d_ws, size_t ws_size,
                              hipStream_t stream) {
    const float* D   = (const float*)d_in[0];
    const float* Ang = (const float*)d_in[1];
    const int*   id3 = (const int*)d_in[2];
    float* out = (float*)d_out;
    int nE = in_sizes[0];
    int nT = in_sizes[1];

    size_t tab_bytes = (size_t)nE * NE_PAD * sizeof(float);
    if (ws_size >= tab_bytes + 512) {
        float* tab = (float*)d_ws;
        float* cst = (float*)((char*)d_ws + tab_bytes);
        setup_k<<<1, 704, 0, stream>>>(cst);
        int gA = (nE + EPB2 - 1) / EPB2;
        edge_k<<<gA, 448, 0, stream>>>(D, cst, tab, nE);
        int gB = (nT + BLK - 1) / BLK;
        trip_k<<<gB, BLK, 0, stream>>>(Ang, id3, tab, cst, out, nT);
    } else {
        float* cst = (float*)d_ws;   // 91 floats
        setup_k<<<1, 704, 0, stream>>>(cst);
        int grid = (nT + BLK - 1) / BLK;
        sph_main<<<grid, BLK, 0, stream>>>(D, Ang, id3, cst, out, nT);
    }
}